// Round 15
// baseline (759.920 us; speedup 1.0000x reference)
//
#include <hip/hip_runtime.h>
#include <cstdint>

typedef __attribute__((ext_vector_type(8))) short bf16x8;
typedef __attribute__((ext_vector_type(4))) float f32x4;

#define B_ 2
#define N_ 2048
#define IN_DIM_ 512
#define D_ 1024
#define H_ 16

__device__ __forceinline__ unsigned short f2bf(float f) {
  uint32_t u = __float_as_uint(f);
  u = u + 0x7fffu + ((u >> 16) & 1u);
  return (unsigned short)(u >> 16);
}
__device__ __forceinline__ float bf2f(unsigned short b) {
  return __uint_as_float(((uint32_t)b) << 16);
}

// async global->LDS, 16B per lane; lds dst is wave-uniform base (+lane*16 by HW)
__device__ __forceinline__ void gll16(const void* g, void* l) {
  __builtin_amdgcn_global_load_lds(
      (const __attribute__((address_space(1))) uint32_t*)g,
      (__attribute__((address_space(3))) uint32_t*)l, 16, 0, 0);
}

// ---------------- elementwise cast fp32 -> bf16 ----------------
__global__ __launch_bounds__(256) void cast_bf16(const float* __restrict__ X,
                                                 unsigned short* __restrict__ O, int n) {
  int i = (blockIdx.x * 256 + threadIdx.x) * 4;
  if (i + 3 < n) {
    f32x4 v = *(const f32x4*)(X + i);
    uint32_t p0 = (uint32_t)f2bf(v[0]) | ((uint32_t)f2bf(v[1]) << 16);
    uint32_t p1 = (uint32_t)f2bf(v[2]) | ((uint32_t)f2bf(v[3]) << 16);
    *(uint32_t*)(O + i) = p0;
    *(uint32_t*)(O + i + 2) = p1;
  }
}

// ---------------- dual cast: two fp32 arrays -> bf16 in one launch ----------------
__global__ __launch_bounds__(256) void cast_bf16x2(const float* __restrict__ X0,
                                                   const float* __restrict__ X1,
                                                   unsigned short* __restrict__ O0,
                                                   unsigned short* __restrict__ O1, int n) {
  int i = (blockIdx.x * 256 + threadIdx.x) * 4;
  const bool second = (i >= n);
  const int j = second ? i - n : i;
  const float* X = second ? X1 : X0;
  unsigned short* O = second ? O1 : O0;
  f32x4 v = *(const f32x4*)(X + j);
  uint32_t p0 = (uint32_t)f2bf(v[0]) | ((uint32_t)f2bf(v[1]) << 16);
  uint32_t p1 = (uint32_t)f2bf(v[2]) | ((uint32_t)f2bf(v[3]) << 16);
  *(uint32_t*)(O + j) = p0;
  *(uint32_t*)(O + j + 2) = p1;
}

// ---------------- transpose + cast: W[K][N] fp32 -> WT[N][K] bf16 ----------------
__global__ __launch_bounds__(256) void transpose_cast(const float* __restrict__ W,
                                                      unsigned short* __restrict__ WT,
                                                      int K, int N) {
  __shared__ float t[32][33];
  const int tx = threadIdx.x, ty = threadIdx.y;
  const int x = blockIdx.x * 32 + tx;   // N index
  const int y = blockIdx.y * 32 + ty;   // K index
  #pragma unroll
  for (int i = 0; i < 4; ++i)
    t[ty + i * 8][tx] = W[(size_t)(y + i * 8) * N + x];
  __syncthreads();
  const int ox = blockIdx.y * 32 + tx;  // K index (contiguous out)
  #pragma unroll
  for (int i = 0; i < 4; ++i) {
    const int oy = blockIdx.x * 32 + ty + i * 8; // N index
    WT[(size_t)oy * K + ox] = f2bf(t[tx][ty + i * 8]);
  }
}

// ---------------- embed GEMM: h = X@emb_w + b + pe, bf16 out ----------------
__global__ __launch_bounds__(256) void gemm_embed(
    const unsigned short* __restrict__ Xbf, const unsigned short* __restrict__ EbT,
    const float* __restrict__ emb_b, unsigned short* __restrict__ Hbf) {
  const int tid = threadIdx.x, l = tid & 63, w = tid >> 6;
  const int wm = w >> 1, wn = w & 1;
  const int bm = blockIdx.y * 128, bn = blockIdx.x * 128;
  __shared__ unsigned short As[128 * 32], Bs[128 * 32];
  const unsigned short* Ab = Xbf + (size_t)bm * IN_DIM_;
  const unsigned short* Bb = EbT + (size_t)bn * IN_DIM_;
  f32x4 acc[4][4] = {};
  const int lr = l >> 2, lc = (l & 3) * 8;
  for (int k0 = 0; k0 < IN_DIM_; k0 += 32) {
    #pragma unroll
    for (int i = 0; i < 2; ++i) {
      const int c = w * 2 + i;
      gll16(Ab + (size_t)(c * 16 + lr) * IN_DIM_ + k0 + lc, As + c * 512);
      gll16(Bb + (size_t)(c * 16 + lr) * IN_DIM_ + k0 + lc, Bs + c * 512);
    }
    __syncthreads();
    bf16x8 af[4], bfr[4];
    #pragma unroll
    for (int f = 0; f < 4; ++f) {
      af[f]  = *(const bf16x8*)(As + (wm * 64 + f * 16 + (l & 15)) * 32 + (l >> 4) * 8);
      bfr[f] = *(const bf16x8*)(Bs + (wn * 64 + f * 16 + (l & 15)) * 32 + (l >> 4) * 8);
    }
    #pragma unroll
    for (int fr = 0; fr < 4; ++fr)
      #pragma unroll
      for (int fc = 0; fc < 4; ++fc)
        acc[fr][fc] = __builtin_amdgcn_mfma_f32_16x16x32_bf16(af[fr], bfr[fc], acc[fr][fc], 0, 0, 0);
    __syncthreads();
  }
  const float kF = -0.017988946039015983f; // -2*ln(10000)/1024
  #pragma unroll
  for (int fr = 0; fr < 4; ++fr) {
    #pragma unroll
    for (int fc = 0; fc < 4; ++fc) {
      const int col = bn + wn * 64 + fc * 16 + (l & 15);
      const float eb = emb_b[col];
      const float fac = expf((float)(col >> 1) * kF);
      #pragma unroll
      for (int j = 0; j < 4; ++j) {
        const int row = bm + wm * 64 + fr * 16 + (l >> 4) * 4 + j;
        const float pos = (float)(row & (N_ - 1));
        const float ang = pos * fac;
        const float pe = (col & 1) ? cosf(ang) : sinf(ang);
        float v = acc[fr][fc][j] + eb + pe;
        float o = __shfl_xor(v, 1);
        unsigned short mb = f2bf(v), ob = f2bf(o);
        uint32_t pk = (l & 1) ? ((uint32_t)ob | ((uint32_t)mb << 16))
                              : ((uint32_t)mb | ((uint32_t)ob << 16));
        const bool mine = (l & 1) ? (j >= 2) : (j < 2);
        if (mine)
          *(uint32_t*)(Hbf + (size_t)row * D_ + (col & ~1)) = pk;
      }
    }
  }
}

// ---------------- generic NT GEMM 128x128 tile, BK=64, bf16 out (XCD swizzle) ----
__global__ __launch_bounds__(256) void gemm_nt(
    const unsigned short* __restrict__ A, const unsigned short* __restrict__ Bm,
    unsigned short* __restrict__ O, int K, long aZ, long bZ, long oZ, int swz) {
  int bx = blockIdx.x, by = blockIdx.y, bz = blockIdx.z;
  if (swz) {
    const int nx = gridDim.x, ny = gridDim.y;
    const int nwg = nx * ny * gridDim.z;
    const int bid = bx + nx * (by + ny * bz);
    const int wid = (bid & 7) * (nwg >> 3) + (bid >> 3);  // bijective (nwg%8==0)
    bx = wid % nx;
    const int rest = wid / nx;
    by = rest % ny;
    bz = rest / ny;
  }
  const int z = bz;
  const int tid = threadIdx.x, l = tid & 63, w = tid >> 6;
  const int wm = w >> 1, wn = w & 1;
  const int bm = by * 128, bn = bx * 128;
  const int ldo = gridDim.x * 128;
  __shared__ unsigned short As[2 * 128 * 32], Bs[2 * 128 * 32];  // [half][128r][32c]
  const unsigned short* Ab = A + (size_t)z * aZ + (size_t)bm * K;
  const unsigned short* Bb = Bm + (size_t)z * bZ + (size_t)bn * K;
  f32x4 acc[4][4] = {};
  const int lr = l >> 2, lc = (l & 3) * 8;
  for (int k0 = 0; k0 < K; k0 += 64) {
    #pragma unroll
    for (int half = 0; half < 2; ++half) {
      #pragma unroll
      for (int i = 0; i < 2; ++i) {
        const int c = w * 2 + i;
        gll16(Ab + (size_t)(c * 16 + lr) * K + k0 + half * 32 + lc,
              As + half * 4096 + c * 512);
        gll16(Bb + (size_t)(c * 16 + lr) * K + k0 + half * 32 + lc,
              Bs + half * 4096 + c * 512);
      }
    }
    __syncthreads();
    #pragma unroll
    for (int half = 0; half < 2; ++half) {
      bf16x8 af[4], bfr[4];
      #pragma unroll
      for (int f = 0; f < 4; ++f) {
        af[f]  = *(const bf16x8*)(As + half * 4096 + (wm * 64 + f * 16 + (l & 15)) * 32 + (l >> 4) * 8);
        bfr[f] = *(const bf16x8*)(Bs + half * 4096 + (wn * 64 + f * 16 + (l & 15)) * 32 + (l >> 4) * 8);
      }
      #pragma unroll
      for (int fr = 0; fr < 4; ++fr)
        #pragma unroll
        for (int fc = 0; fc < 4; ++fc)
          acc[fr][fc] = __builtin_amdgcn_mfma_f32_16x16x32_bf16(af[fr], bfr[fc], acc[fr][fc], 0, 0, 0);
    }
    __syncthreads();
  }
  unsigned short* obase = O + (size_t)z * oZ;
  #pragma unroll
  for (int fr = 0; fr < 4; ++fr) {
    #pragma unroll
    for (int fc = 0; fc < 4; ++fc) {
      const int col = bn + wn * 64 + fc * 16 + (l & 15);
      #pragma unroll
      for (int j = 0; j < 4; ++j) {
        const int row = bm + wm * 64 + fr * 16 + (l >> 4) * 4 + j;
        float v = acc[fr][fc][j];
        float o = __shfl_xor(v, 1);
        unsigned short mb = f2bf(v), ob = f2bf(o);
        uint32_t pk = (l & 1) ? ((uint32_t)ob | ((uint32_t)mb << 16))
                              : ((uint32_t)mb | ((uint32_t)ob << 16));
        const bool mine = (l & 1) ? (j >= 2) : (j < 2);
        if (mine)
          *(uint32_t*)(obase + (size_t)row * ldo + (col & ~1)) = pk;
      }
    }
  }
}

// ---------------- fused: V = h @ Wv (blocks 0..1023) + M = Wo@dec_w (1024..1087) ----
__global__ __launch_bounds__(256) void v_wodec_kernel(
    const unsigned short* __restrict__ Hbf, const float* __restrict__ Wv,
    float* __restrict__ V, const float* __restrict__ Wo,
    const float* __restrict__ dec_w, float* __restrict__ M) {
  if (blockIdx.x < 1024) {
    const int l = threadIdx.x & 63, w = threadIdx.x >> 6;
    const int ng = blockIdx.x * 4 + w;          // [0, 4096)
    const int b = ng >> 11, n = ng & (N_ - 1);
    const unsigned short* hr = Hbf + (size_t)ng * D_;
    float hv[16];
    #pragma unroll
    for (int i = 0; i < 2; ++i) {
      bf16x8 x = *(const bf16x8*)(hr + l * 16 + i * 8);
      #pragma unroll
      for (int j = 0; j < 8; ++j) hv[i * 8 + j] = bf2f((unsigned short)x[j]);
    }
    for (int h = 0; h < H_; ++h) {
      const float* wr = Wv + (size_t)h * D_ + l * 16;
      float s = 0.f;
      #pragma unroll
      for (int i = 0; i < 4; ++i) {
        f32x4 w4 = *(const f32x4*)(wr + i * 4);
        s += hv[i*4+0]*w4[0] + hv[i*4+1]*w4[1] + hv[i*4+2]*w4[2] + hv[i*4+3]*w4[3];
      }
      #pragma unroll
      for (int m = 1; m < 64; m <<= 1) s += __shfl_xor(s, m);
      if (l == 0) V[((size_t)b * H_ + h) * N_ + n] = s;
    }
  } else {
    const int idx = (blockIdx.x - 1024) * 256 + threadIdx.x;
    const int h = idx >> 10, c = idx & 1023;
    float s = 0.f;
    #pragma unroll 4
    for (int d = 0; d < D_; ++d) s += Wo[h * D_ + d] * dec_w[(size_t)d * 1024 + c];
    M[idx] = s;
  }
}

// ---------------- score_flash v14: 256x256 tile, 8 waves, 4-phase interleave ----
// Per K-tile (BK=64): 4 phases, each {ds_read frags; stage 2 next-tile 8KB units;
// counted vmcnt (never 0 mid-loop); barrier; setprio+16 MFMA; barrier}.
// LDS: 2 buffers x (A[256][64] + B[256][64]) = 128 KB, 3-bit XOR chunk swizzle
// (pc = c ^ (row&7)) -> 2-way-max bank aliasing on ds_read_b128 (free).
// Stage order per tile: B0-127, B128-255, A{0-63,128-191}, A{64-127,192-255};
// waits: r==1 -> vmcnt(4), r==3 -> vmcnt(2) (final tile: vmcnt(0) at r==1).
// Epilogue: fixed-shift softmax partials (sum_e, sum_ev), 4-way wn-merge in LDS.
__global__ __launch_bounds__(512, 2) void score_flash(
    const unsigned short* __restrict__ G, const unsigned short* __restrict__ Hb,
    const float* __restrict__ V, float* __restrict__ Pp) {
  extern __shared__ unsigned short KQ[];  // 2 x 32768 shorts
  const int bid = blockIdx.x;
  const int wid = (bid & 7) * 128 + (bid >> 3);  // bijective: 1024 % 8 == 0
  const int kt = wid & 7, qt = (wid >> 3) & 7, h = wid >> 6;
  const int tid = threadIdx.x;
  const int l = tid & 63, l15 = l & 15, l7 = l & 7, lq = l >> 4;
  const int wv = tid >> 6, wm = wv >> 2, wn = wv & 3;
  const unsigned short* Ab = G + ((size_t)h * N_ + qt * 256) * D_;
  const unsigned short* Bb = Hb + (size_t)(kt * 256) * D_;
  const float* Vf = V + (size_t)h * N_;

  // stage one 8KB unit (64 rows x 64 cols): 1 gll16/thread, inverse-swizzled src
  const int srow = tid >> 3, spc = tid & 7, scol = (spc ^ (srow & 7)) * 8;
  auto stageU = [&](const unsigned short* src, int rowBase, int k0, unsigned short* ldsU) {
    gll16(src + (size_t)(rowBase + srow) * D_ + k0 + scol, ldsU + tid * 8);
  };

  float vv[4];
  #pragma unroll
  for (int fc = 0; fc < 4; ++fc)
    vv[fc] = Vf[kt * 256 + wn * 64 + fc * 16 + l15];

  // prologue: tile 0 (k0=0); A-high units issued last
  {
    unsigned short* A0 = KQ;
    unsigned short* B0 = KQ + 16384;
    stageU(Bb, 0, 0, B0); stageU(Bb, 64, 0, B0 + 4096);
    stageU(Bb, 128, 0, B0 + 8192); stageU(Bb, 192, 0, B0 + 12288);
    stageU(Ab, 0, 0, A0); stageU(Ab, 128, 0, A0 + 8192);
    stageU(Ab, 64, 0, A0 + 4096); stageU(Ab, 192, 0, A0 + 12288);
  }
  __builtin_amdgcn_sched_barrier(0);
  asm volatile("s_waitcnt vmcnt(2)" ::: "memory");
  __builtin_amdgcn_s_barrier();
  __builtin_amdgcn_sched_barrier(0);

  f32x4 acc[8][4] = {};
  const int arow0 = wm * 128 + l15;           // + fr*16
  const int brow0 = wn * 64 + l15;            // + fc*16

  for (int t = 0; t < 16; ++t) {
    unsigned short* Acur = KQ + (t & 1) * 32768;
    unsigned short* Bcur = Acur + 16384;
    unsigned short* Anxt = KQ + ((t & 1) ^ 1) * 32768;
    unsigned short* Bnxt = Anxt + 16384;
    const int k0n = (t + 1) * 64;
    const bool more = (t < 15);
    bf16x8 bfr[4][2];
    #pragma unroll
    for (int r = 0; r < 4; ++r) {
      // ---- frag reads from current buffer ----
      if (r == 0) {
        #pragma unroll
        for (int fc = 0; fc < 4; ++fc)
          #pragma unroll
          for (int kh = 0; kh < 2; ++kh)
            bfr[fc][kh] = *(const bf16x8*)(Bcur + (brow0 + fc * 16) * 64 +
                                           (((kh * 4 + lq) ^ l7) * 8));
      }
      bf16x8 af[2][2];
      #pragma unroll
      for (int i = 0; i < 2; ++i)
        #pragma unroll
        for (int kh = 0; kh < 2; ++kh)
          af[i][kh] = *(const bf16x8*)(Acur + (arow0 + (2 * r + i) * 16) * 64 +
                                       (((kh * 4 + lq) ^ l7) * 8));
      // ---- stage next tile's units (B first, A-low, A-high last) ----
      if (more) {
        if (r == 0)      { stageU(Bb, 0, k0n, Bnxt);        stageU(Bb, 64, k0n, Bnxt + 4096); }
        else if (r == 1) { stageU(Bb, 128, k0n, Bnxt + 8192); stageU(Bb, 192, k0n, Bnxt + 12288); }
        else if (r == 2) { stageU(Ab, 0, k0n, Anxt);        stageU(Ab, 128, k0n, Anxt + 8192); }
        else             { stageU(Ab, 64, k0n, Anxt + 4096); stageU(Ab, 192, k0n, Anxt + 12288); }
      }
      __builtin_amdgcn_sched_barrier(0);
      // ---- counted waits: never drain to 0 mid-loop ----
      if (r == 1) {
        if (t == 15) asm volatile("s_waitcnt vmcnt(0)" ::: "memory");
        else         asm volatile("s_waitcnt vmcnt(4)" ::: "memory");
      }
      if (r == 3 && more) asm volatile("s_waitcnt vmcnt(2)" ::: "memory");
      __builtin_amdgcn_s_barrier();
      __builtin_amdgcn_sched_barrier(0);
      // ---- MFMA cluster ----
      __builtin_amdgcn_s_setprio(1);
      #pragma unroll
      for (int i = 0; i < 2; ++i)
        #pragma unroll
        for (int fc = 0; fc < 4; ++fc)
          #pragma unroll
          for (int kh = 0; kh < 2; ++kh)
            acc[2 * r + i][fc] = __builtin_amdgcn_mfma_f32_16x16x32_bf16(
                af[i][kh], bfr[fc][kh], acc[2 * r + i][fc], 0, 0, 0);
      __builtin_amdgcn_s_setprio(0);
      __builtin_amdgcn_sched_barrier(0);
      __builtin_amdgcn_s_barrier();
      __builtin_amdgcn_sched_barrier(0);
    }
  }

  // ---- epilogue: fixed-shift partials, wn-merge in LDS ----
  __syncthreads();
  float* sb = (float*)KQ;  // [256 q_local][4 wn][2]
  #pragma unroll
  for (int fr = 0; fr < 8; ++fr) {
    #pragma unroll
    for (int j = 0; j < 4; ++j) {
      float s4[4];
      #pragma unroll
      for (int fc = 0; fc < 4; ++fc) s4[fc] = acc[fr][fc][j] * 0.03125f;
      if (kt == 0 && wn == 0 && l15 == 0) s4[0] = 0.0f;  // mask global col 0
      float ps = 0.f, pv = 0.f;
      #pragma unroll
      for (int fc = 0; fc < 4; ++fc) {
        const float e = __expf(s4[fc] - 8.0f);
        ps += e; pv += e * vv[fc];
      }
      ps += __shfl_xor(ps, 1); pv += __shfl_xor(pv, 1);
      ps += __shfl_xor(ps, 2); pv += __shfl_xor(pv, 2);
      ps += __shfl_xor(ps, 4); pv += __shfl_xor(pv, 4);
      ps += __shfl_xor(ps, 8); pv += __shfl_xor(pv, 8);
      if (l15 == 0) {
        const int q = wm * 128 + fr * 16 + lq * 4 + j;
        sb[(q * 4 + wn) * 2 + 0] = ps;
        sb[(q * 4 + wn) * 2 + 1] = pv;
      }
    }
  }
  __syncthreads();
  if (tid < 256) {
    const int q = tid;
    float L = 0.f, O = 0.f;
    #pragma unroll
    for (int n = 0; n < 4; ++n) { L += sb[(q * 4 + n) * 2]; O += sb[(q * 4 + n) * 2 + 1]; }
    float* p = Pp + (((size_t)h * 8 + kt) * N_ + qt * 256 + q) * 2;
    p[0] = L; p[1] = O;
  }
}

// ---------------- merge 8 kt partials -> ctx (plain sums) ----------------
__global__ __launch_bounds__(256) void merge8(const float* __restrict__ Pp,
                                              float* __restrict__ ctx) {
  const int idx = blockIdx.x * 256 + threadIdx.x;  // [0, 32768)
  const int h = idx >> 11, q = idx & (N_ - 1);
  float L = 0.f, O = 0.f;
  #pragma unroll
  for (int kt = 0; kt < 8; ++kt) {
    const float* p = Pp + (((size_t)h * 8 + kt) * N_ + q) * 2;
    L += p[0]; O += p[1];
  }
  ctx[(size_t)q * H_ + h] = O / L;
}

// ---------------- out = ctx @ M + dec_b ----------------
__global__ __launch_bounds__(256) void final_kernel(
    const float* __restrict__ ctx, const float* __restrict__ M,
    const float* __restrict__ dec_b, float* __restrict__ out) {
  const int idx = blockIdx.x * 256 + threadIdx.x;
  const int c = idx & 1023;
  const float* cr = ctx + (size_t)(idx >> 10) * H_;
  float s = dec_b[c];
  #pragma unroll
  for (int h = 0; h < H_; ++h) s += cr[h] * M[h * 1024 + c];
  out[idx] = s;
}

extern "C" void kernel_launch(void* const* d_in, const int* in_sizes, int n_in,
                              void* d_out, int out_size, void* d_ws, size_t ws_size,
                              hipStream_t stream) {
  const float* X     = (const float*)d_in[0];
  const float* emb_w = (const float*)d_in[1];
  const float* emb_b = (const float*)d_in[2];
  const float* Wq    = (const float*)d_in[3];
  const float* Wk    = (const float*)d_in[4];
  const float* Wv    = (const float*)d_in[5];
  const float* Wo    = (const float*)d_in[6];
  const float* dec_b = (const float*)d_in[8];
  const float* dec_w = (const float*)d_in[7];
  float* out = (float*)d_out;
  (void)in_sizes; (void)n_in; (void)out_size;

  char* ws = (char*)d_ws;
  // persistent region: 41 MB
  unsigned short* Hbf = (unsigned short*)(ws);                              // 8 MB  [4096][1024]
  unsigned short* Wkq = (unsigned short*)(ws + ((size_t)8 << 20));          // 32 MB [16][1024][1024]
  float* Vb  = (float*)(ws + ((size_t)40 << 20));                          // 256 KB [2][16][2048]
  float* ctx = (float*)(ws + ((size_t)40 << 20) + ((size_t)256 << 10));    // 256 KB [4096][16]
  float* Mw  = (float*)(ws + ((size_t)40 << 20) + ((size_t)512 << 10));    // 64 KB  [16][1024]
  // scratch region S (64 MB), phase-aliased
  char* S = ws + ((size_t)41 << 20);
  unsigned short* Xbf  = (unsigned short*)(S);                              // 4 MB
  unsigned short* EbT  = (unsigned short*)(S + ((size_t)4 << 20));          // 1 MB
  unsigned short* Wqbf = (unsigned short*)(S);                              // 32 MB
  unsigned short* Wkbf = (unsigned short*)(S + ((size_t)32 << 20));         // 32 MB
  unsigned short* G    = (unsigned short*)(S);                              // 64 MB [16][2048][1024]
  // score partials live in d_out (dead until final_kernel): 16*8*2048*2*4 = 2.1 MB
  float* Pp = (float*)d_out;

  const size_t need = ((size_t)41 << 20) + ((size_t)64 << 20);  // 105 MB
  if (ws_size < need) return;  // clean fail -> diagnostic (ws too small)

  cast_bf16<<<2048, 256, 0, stream>>>(X, Xbf, B_ * N_ * IN_DIM_);
  transpose_cast<<<dim3(32, 16, 1), dim3(32, 8), 0, stream>>>(emb_w, EbT, IN_DIM_, D_);
  gemm_embed<<<dim3(8, 32), 256, 0, stream>>>(Xbf, EbT, emb_b, Hbf);
  // Wkq[h] = Wk[h] @ Wq[h]^T  (so that G = h @ Wkq^T = h @ (Wq Wk^T))
  cast_bf16x2<<<32768, 256, 0, stream>>>(Wq, Wk, Wqbf, Wkbf, H_ * D_ * D_);
  gemm_nt<<<dim3(8, 8, 16), 256, 0, stream>>>(Wkbf, Wqbf, Wkq, D_,
                                              (long)D_ * D_, (long)D_ * D_, (long)D_ * D_, 1);
  v_wodec_kernel<<<1088, 256, 0, stream>>>(Hbf, Wv, Vb, Wo, dec_w, Mw);

  for (int b = 0; b < B_; ++b) {
    const unsigned short* Hb = Hbf + (size_t)b * N_ * D_;
    gemm_nt<<<dim3(8, 16, 16), 256, 0, stream>>>(Hb, Wkq, G, D_,
                                                 0L, (long)D_ * D_, (long)N_ * D_, 1);
    score_flash<<<1024, 512, 131072, stream>>>(G, Hb, Vb + (size_t)b * H_ * N_, Pp);
    merge8<<<128, 256, 0, stream>>>(Pp, ctx + (size_t)b * N_ * H_);
  }
  final_kernel<<<16384, 256, 0, stream>>>(ctx, Mw, dec_b, out);
}

// Round 19
// 699.613 us; speedup vs baseline: 1.0862x; 1.0862x over previous
//
#include <hip/hip_runtime.h>
#include <cstdint>

typedef __attribute__((ext_vector_type(8))) short bf16x8;
typedef __attribute__((ext_vector_type(4))) float f32x4;

#define B_ 2
#define N_ 2048
#define IN_DIM_ 512
#define D_ 1024
#define H_ 16

__device__ __forceinline__ unsigned short f2bf(float f) {
  uint32_t u = __float_as_uint(f);
  u = u + 0x7fffu + ((u >> 16) & 1u);
  return (unsigned short)(u >> 16);
}
__device__ __forceinline__ float bf2f(unsigned short b) {
  return __uint_as_float(((uint32_t)b) << 16);
}

// async global->LDS, 16B per lane; lds dst is wave-uniform base (+lane*16 by HW)
__device__ __forceinline__ void gll16(const void* g, void* l) {
  __builtin_amdgcn_global_load_lds(
      (const __attribute__((address_space(1))) uint32_t*)g,
      (__attribute__((address_space(3))) uint32_t*)l, 16, 0, 0);
}

// ---------------- prep: cast X -> bf16 (blocks 0..2047) + transpose emb_w (2048..2559) ----
__global__ __launch_bounds__(256) void prep_kernel(
    const float* __restrict__ X, unsigned short* __restrict__ Xbf,
    const float* __restrict__ emb_w, unsigned short* __restrict__ EbT) {
  __shared__ float t[32][33];
  const int tid = threadIdx.x;
  if (blockIdx.x < 2048) {
    const int i = (blockIdx.x * 256 + tid) * 4;
    if (i + 3 < B_ * N_ * IN_DIM_) {
      f32x4 v = *(const f32x4*)(X + i);
      uint32_t p0 = (uint32_t)f2bf(v[0]) | ((uint32_t)f2bf(v[1]) << 16);
      uint32_t p1 = (uint32_t)f2bf(v[2]) | ((uint32_t)f2bf(v[3]) << 16);
      *(uint32_t*)(Xbf + i) = p0;
      *(uint32_t*)(Xbf + i + 2) = p1;
    }
  } else {
    const int tb = blockIdx.x - 2048;
    const int bx = tb & 31, by = tb >> 5;      // 32 N-tiles x 16 K-tiles
    const int tx = tid & 31, ty = tid >> 5;
    const int x = bx * 32 + tx;                // N index (1024)
    const int y = by * 32 + ty;                // K index (512)
    #pragma unroll
    for (int i = 0; i < 4; ++i)
      t[ty + i * 8][tx] = emb_w[(size_t)(y + i * 8) * D_ + x];
    __syncthreads();
    const int ox = by * 32 + tx;               // K index
    #pragma unroll
    for (int i = 0; i < 4; ++i) {
      const int oy = bx * 32 + ty + i * 8;     // N index
      EbT[(size_t)oy * IN_DIM_ + ox] = f2bf(t[tx][ty + i * 8]);
    }
  }
}

// ---------------- dual cast: two fp32 arrays -> bf16 in one launch ----------------
__global__ __launch_bounds__(256) void cast_bf16x2(const float* __restrict__ X0,
                                                   const float* __restrict__ X1,
                                                   unsigned short* __restrict__ O0,
                                                   unsigned short* __restrict__ O1, int n) {
  int i = (blockIdx.x * 256 + threadIdx.x) * 4;
  const bool second = (i >= n);
  const int j = second ? i - n : i;
  const float* X = second ? X1 : X0;
  unsigned short* O = second ? O1 : O0;
  f32x4 v = *(const f32x4*)(X + j);
  uint32_t p0 = (uint32_t)f2bf(v[0]) | ((uint32_t)f2bf(v[1]) << 16);
  uint32_t p1 = (uint32_t)f2bf(v[2]) | ((uint32_t)f2bf(v[3]) << 16);
  *(uint32_t*)(O + j) = p0;
  *(uint32_t*)(O + j + 2) = p1;
}

// ---------------- embed GEMM: h = X@emb_w + b + pe, bf16 out ----------------
__global__ __launch_bounds__(256) void gemm_embed(
    const unsigned short* __restrict__ Xbf, const unsigned short* __restrict__ EbT,
    const float* __restrict__ emb_b, unsigned short* __restrict__ Hbf) {
  const int tid = threadIdx.x, l = tid & 63, w = tid >> 6;
  const int wm = w >> 1, wn = w & 1;
  const int bm = blockIdx.y * 128, bn = blockIdx.x * 128;
  __shared__ unsigned short As[128 * 32], Bs[128 * 32];
  const unsigned short* Ab = Xbf + (size_t)bm * IN_DIM_;
  const unsigned short* Bb = EbT + (size_t)bn * IN_DIM_;
  f32x4 acc[4][4] = {};
  const int lr = l >> 2, lc = (l & 3) * 8;
  for (int k0 = 0; k0 < IN_DIM_; k0 += 32) {
    #pragma unroll
    for (int i = 0; i < 2; ++i) {
      const int c = w * 2 + i;
      gll16(Ab + (size_t)(c * 16 + lr) * IN_DIM_ + k0 + lc, As + c * 512);
      gll16(Bb + (size_t)(c * 16 + lr) * IN_DIM_ + k0 + lc, Bs + c * 512);
    }
    __syncthreads();
    bf16x8 af[4], bfr[4];
    #pragma unroll
    for (int f = 0; f < 4; ++f) {
      af[f]  = *(const bf16x8*)(As + (wm * 64 + f * 16 + (l & 15)) * 32 + (l >> 4) * 8);
      bfr[f] = *(const bf16x8*)(Bs + (wn * 64 + f * 16 + (l & 15)) * 32 + (l >> 4) * 8);
    }
    #pragma unroll
    for (int fr = 0; fr < 4; ++fr)
      #pragma unroll
      for (int fc = 0; fc < 4; ++fc)
        acc[fr][fc] = __builtin_amdgcn_mfma_f32_16x16x32_bf16(af[fr], bfr[fc], acc[fr][fc], 0, 0, 0);
    __syncthreads();
  }
  const float kF = -0.017988946039015983f; // -2*ln(10000)/1024
  #pragma unroll
  for (int fr = 0; fr < 4; ++fr) {
    #pragma unroll
    for (int fc = 0; fc < 4; ++fc) {
      const int col = bn + wn * 64 + fc * 16 + (l & 15);
      const float eb = emb_b[col];
      const float fac = expf((float)(col >> 1) * kF);
      #pragma unroll
      for (int j = 0; j < 4; ++j) {
        const int row = bm + wm * 64 + fr * 16 + (l >> 4) * 4 + j;
        const float pos = (float)(row & (N_ - 1));
        const float ang = pos * fac;
        const float pe = (col & 1) ? cosf(ang) : sinf(ang);
        float v = acc[fr][fc][j] + eb + pe;
        float o = __shfl_xor(v, 1);
        unsigned short mb = f2bf(v), ob = f2bf(o);
        uint32_t pk = (l & 1) ? ((uint32_t)ob | ((uint32_t)mb << 16))
                              : ((uint32_t)mb | ((uint32_t)ob << 16));
        const bool mine = (l & 1) ? (j >= 2) : (j < 2);
        if (mine)
          *(uint32_t*)(Hbf + (size_t)row * D_ + (col & ~1)) = pk;
      }
    }
  }
}

// ---------------- gemm_nt256: 256x256 tile, 8 waves, 4-phase counted-vmcnt ----
// Same schedule as score_flash v14 (proven): 2-buffer 128KB LDS, 3-bit XOR chunk
// swizzle, stage order B0,B1,B2,B3,A0,A2,A1,A3; waits vmcnt(4)@r1 / vmcnt(2)@r3,
// never 0 mid-loop. Epilogue: plain bf16 store (shfl-pair packed u32).
__global__ __launch_bounds__(512, 2) void gemm_nt256(
    const unsigned short* __restrict__ A, const unsigned short* __restrict__ Bm,
    unsigned short* __restrict__ O, int K, long aZ, long bZ, long oZ,
    int nbx, int nby, int ldo) {
  extern __shared__ unsigned short KQ[];  // 2 x 32768 shorts
  const int nb = gridDim.x;
  const int bid = blockIdx.x;
  const int wid = (bid & 7) * (nb >> 3) + (bid >> 3);  // bijective (nb%8==0)
  const int bxi = wid % nbx;
  const int rest = wid / nbx;
  const int byi = rest % nby;
  const int z = rest / nby;
  const int tid = threadIdx.x;
  const int l = tid & 63, l15 = l & 15, l7 = l & 7, lq = l >> 4;
  const int wv = tid >> 6, wm = wv >> 2, wn = wv & 3;
  const unsigned short* Ab = A + (size_t)z * aZ + (size_t)(byi * 256) * K;
  const unsigned short* Bb = Bm + (size_t)z * bZ + (size_t)(bxi * 256) * K;

  const int srow = tid >> 3, spc = tid & 7, scol = (spc ^ (srow & 7)) * 8;
  auto stageU = [&](const unsigned short* src, int rowBase, int k0, unsigned short* ldsU) {
    gll16(src + (size_t)(rowBase + srow) * K + k0 + scol, ldsU + tid * 8);
  };

  // prologue: tile 0
  {
    unsigned short* A0 = KQ;
    unsigned short* B0 = KQ + 16384;
    stageU(Bb, 0, 0, B0); stageU(Bb, 64, 0, B0 + 4096);
    stageU(Bb, 128, 0, B0 + 8192); stageU(Bb, 192, 0, B0 + 12288);
    stageU(Ab, 0, 0, A0); stageU(Ab, 128, 0, A0 + 8192);
    stageU(Ab, 64, 0, A0 + 4096); stageU(Ab, 192, 0, A0 + 12288);
  }
  __builtin_amdgcn_sched_barrier(0);
  asm volatile("s_waitcnt vmcnt(2)" ::: "memory");
  __builtin_amdgcn_s_barrier();
  __builtin_amdgcn_sched_barrier(0);

  f32x4 acc[8][4] = {};
  const int arow0 = wm * 128 + l15;
  const int brow0 = wn * 64 + l15;
  const int nt = K >> 6;

  for (int t = 0; t < nt; ++t) {
    unsigned short* Acur = KQ + (t & 1) * 32768;
    unsigned short* Bcur = Acur + 16384;
    unsigned short* Anxt = KQ + ((t & 1) ^ 1) * 32768;
    unsigned short* Bnxt = Anxt + 16384;
    const int k0n = (t + 1) * 64;
    const bool more = (t < nt - 1);
    bf16x8 bfr[4][2];
    #pragma unroll
    for (int r = 0; r < 4; ++r) {
      if (r == 0) {
        #pragma unroll
        for (int fc = 0; fc < 4; ++fc)
          #pragma unroll
          for (int kh = 0; kh < 2; ++kh)
            bfr[fc][kh] = *(const bf16x8*)(Bcur + (brow0 + fc * 16) * 64 +
                                           (((kh * 4 + lq) ^ l7) * 8));
      }
      bf16x8 af[2][2];
      #pragma unroll
      for (int i = 0; i < 2; ++i)
        #pragma unroll
        for (int kh = 0; kh < 2; ++kh)
          af[i][kh] = *(const bf16x8*)(Acur + (arow0 + (2 * r + i) * 16) * 64 +
                                       (((kh * 4 + lq) ^ l7) * 8));
      if (more) {
        if (r == 0)      { stageU(Bb, 0, k0n, Bnxt);          stageU(Bb, 64, k0n, Bnxt + 4096); }
        else if (r == 1) { stageU(Bb, 128, k0n, Bnxt + 8192); stageU(Bb, 192, k0n, Bnxt + 12288); }
        else if (r == 2) { stageU(Ab, 0, k0n, Anxt);          stageU(Ab, 128, k0n, Anxt + 8192); }
        else             { stageU(Ab, 64, k0n, Anxt + 4096);  stageU(Ab, 192, k0n, Anxt + 12288); }
      }
      __builtin_amdgcn_sched_barrier(0);
      if (r == 1) {
        if (t == nt - 1) asm volatile("s_waitcnt vmcnt(0)" ::: "memory");
        else             asm volatile("s_waitcnt vmcnt(4)" ::: "memory");
      }
      if (r == 3 && more) asm volatile("s_waitcnt vmcnt(2)" ::: "memory");
      __builtin_amdgcn_s_barrier();
      __builtin_amdgcn_sched_barrier(0);
      __builtin_amdgcn_s_setprio(1);
      #pragma unroll
      for (int i = 0; i < 2; ++i)
        #pragma unroll
        for (int fc = 0; fc < 4; ++fc)
          #pragma unroll
          for (int kh = 0; kh < 2; ++kh)
            acc[2 * r + i][fc] = __builtin_amdgcn_mfma_f32_16x16x32_bf16(
                af[i][kh], bfr[fc][kh], acc[2 * r + i][fc], 0, 0, 0);
      __builtin_amdgcn_s_setprio(0);
      __builtin_amdgcn_sched_barrier(0);
      __builtin_amdgcn_s_barrier();
      __builtin_amdgcn_sched_barrier(0);
    }
  }

  // epilogue: bf16 store
  unsigned short* obase = O + (size_t)z * oZ + (size_t)(byi * 256) * ldo + bxi * 256;
  #pragma unroll
  for (int fr = 0; fr < 8; ++fr) {
    #pragma unroll
    for (int fc = 0; fc < 4; ++fc) {
      const int col = wn * 64 + fc * 16 + l15;
      #pragma unroll
      for (int j = 0; j < 4; ++j) {
        const int row = wm * 128 + fr * 16 + lq * 4 + j;
        float v = acc[fr][fc][j];
        float o = __shfl_xor(v, 1);
        unsigned short mb = f2bf(v), ob = f2bf(o);
        uint32_t pk = (l & 1) ? ((uint32_t)ob | ((uint32_t)mb << 16))
                              : ((uint32_t)mb | ((uint32_t)ob << 16));
        const bool mine = (l & 1) ? (j >= 2) : (j < 2);
        if (mine)
          *(uint32_t*)(obase + (size_t)row * ldo + (col & ~1)) = pk;
      }
    }
  }
}

// ---------------- fused: V = h @ Wv (blocks 0..1023) + M = Wo@dec_w (1024..1087) ----
__global__ __launch_bounds__(256) void v_wodec_kernel(
    const unsigned short* __restrict__ Hbf, const float* __restrict__ Wv,
    float* __restrict__ V, const float* __restrict__ Wo,
    const float* __restrict__ dec_w, float* __restrict__ M) {
  if (blockIdx.x < 1024) {
    const int l = threadIdx.x & 63, w = threadIdx.x >> 6;
    const int ng = blockIdx.x * 4 + w;          // [0, 4096)
    const int b = ng >> 11, n = ng & (N_ - 1);
    const unsigned short* hr = Hbf + (size_t)ng * D_;
    float hv[16];
    #pragma unroll
    for (int i = 0; i < 2; ++i) {
      bf16x8 x = *(const bf16x8*)(hr + l * 16 + i * 8);
      #pragma unroll
      for (int j = 0; j < 8; ++j) hv[i * 8 + j] = bf2f((unsigned short)x[j]);
    }
    for (int h = 0; h < H_; ++h) {
      const float* wr = Wv + (size_t)h * D_ + l * 16;
      float s = 0.f;
      #pragma unroll
      for (int i = 0; i < 4; ++i) {
        f32x4 w4 = *(const f32x4*)(wr + i * 4);
        s += hv[i*4+0]*w4[0] + hv[i*4+1]*w4[1] + hv[i*4+2]*w4[2] + hv[i*4+3]*w4[3];
      }
      #pragma unroll
      for (int m = 1; m < 64; m <<= 1) s += __shfl_xor(s, m);
      if (l == 0) V[((size_t)b * H_ + h) * N_ + n] = s;
    }
  } else {
    const int idx = (blockIdx.x - 1024) * 256 + threadIdx.x;
    const int h = idx >> 10, c = idx & 1023;
    float s = 0.f;
    #pragma unroll 4
    for (int d = 0; d < D_; ++d) s += Wo[h * D_ + d] * dec_w[(size_t)d * 1024 + c];
    M[idx] = s;
  }
}

// ---------------- score_flash v14: 256x256 tile, 8 waves, 4-phase interleave ----
__global__ __launch_bounds__(512, 2) void score_flash(
    const unsigned short* __restrict__ G, const unsigned short* __restrict__ Hb,
    const float* __restrict__ V, float* __restrict__ Pp) {
  extern __shared__ unsigned short KQ[];  // 2 x 32768 shorts
  const int bid = blockIdx.x;
  const int wid = (bid & 7) * 128 + (bid >> 3);  // bijective: 1024 % 8 == 0
  const int kt = wid & 7, qt = (wid >> 3) & 7, h = wid >> 6;
  const int tid = threadIdx.x;
  const int l = tid & 63, l15 = l & 15, l7 = l & 7, lq = l >> 4;
  const int wv = tid >> 6, wm = wv >> 2, wn = wv & 3;
  const unsigned short* Ab = G + ((size_t)h * N_ + qt * 256) * D_;
  const unsigned short* Bb = Hb + (size_t)(kt * 256) * D_;
  const float* Vf = V + (size_t)h * N_;

  const int srow = tid >> 3, spc = tid & 7, scol = (spc ^ (srow & 7)) * 8;
  auto stageU = [&](const unsigned short* src, int rowBase, int k0, unsigned short* ldsU) {
    gll16(src + (size_t)(rowBase + srow) * D_ + k0 + scol, ldsU + tid * 8);
  };

  float vv[4];
  #pragma unroll
  for (int fc = 0; fc < 4; ++fc)
    vv[fc] = Vf[kt * 256 + wn * 64 + fc * 16 + l15];

  {
    unsigned short* A0 = KQ;
    unsigned short* B0 = KQ + 16384;
    stageU(Bb, 0, 0, B0); stageU(Bb, 64, 0, B0 + 4096);
    stageU(Bb, 128, 0, B0 + 8192); stageU(Bb, 192, 0, B0 + 12288);
    stageU(Ab, 0, 0, A0); stageU(Ab, 128, 0, A0 + 8192);
    stageU(Ab, 64, 0, A0 + 4096); stageU(Ab, 192, 0, A0 + 12288);
  }
  __builtin_amdgcn_sched_barrier(0);
  asm volatile("s_waitcnt vmcnt(2)" ::: "memory");
  __builtin_amdgcn_s_barrier();
  __builtin_amdgcn_sched_barrier(0);

  f32x4 acc[8][4] = {};
  const int arow0 = wm * 128 + l15;
  const int brow0 = wn * 64 + l15;

  for (int t = 0; t < 16; ++t) {
    unsigned short* Acur = KQ + (t & 1) * 32768;
    unsigned short* Bcur = Acur + 16384;
    unsigned short* Anxt = KQ + ((t & 1) ^ 1) * 32768;
    unsigned short* Bnxt = Anxt + 16384;
    const int k0n = (t + 1) * 64;
    const bool more = (t < 15);
    bf16x8 bfr[4][2];
    #pragma unroll
    for (int r = 0; r < 4; ++r) {
      if (r == 0) {
        #pragma unroll
        for (int fc = 0; fc < 4; ++fc)
          #pragma unroll
          for (int kh = 0; kh < 2; ++kh)
            bfr[fc][kh] = *(const bf16x8*)(Bcur + (brow0 + fc * 16) * 64 +
                                           (((kh * 4 + lq) ^ l7) * 8));
      }
      bf16x8 af[2][2];
      #pragma unroll
      for (int i = 0; i < 2; ++i)
        #pragma unroll
        for (int kh = 0; kh < 2; ++kh)
          af[i][kh] = *(const bf16x8*)(Acur + (arow0 + (2 * r + i) * 16) * 64 +
                                       (((kh * 4 + lq) ^ l7) * 8));
      if (more) {
        if (r == 0)      { stageU(Bb, 0, k0n, Bnxt);          stageU(Bb, 64, k0n, Bnxt + 4096); }
        else if (r == 1) { stageU(Bb, 128, k0n, Bnxt + 8192); stageU(Bb, 192, k0n, Bnxt + 12288); }
        else if (r == 2) { stageU(Ab, 0, k0n, Anxt);          stageU(Ab, 128, k0n, Anxt + 8192); }
        else             { stageU(Ab, 64, k0n, Anxt + 4096);  stageU(Ab, 192, k0n, Anxt + 12288); }
      }
      __builtin_amdgcn_sched_barrier(0);
      if (r == 1) {
        if (t == 15) asm volatile("s_waitcnt vmcnt(0)" ::: "memory");
        else         asm volatile("s_waitcnt vmcnt(4)" ::: "memory");
      }
      if (r == 3 && more) asm volatile("s_waitcnt vmcnt(2)" ::: "memory");
      __builtin_amdgcn_s_barrier();
      __builtin_amdgcn_sched_barrier(0);
      __builtin_amdgcn_s_setprio(1);
      #pragma unroll
      for (int i = 0; i < 2; ++i)
        #pragma unroll
        for (int fc = 0; fc < 4; ++fc)
          #pragma unroll
          for (int kh = 0; kh < 2; ++kh)
            acc[2 * r + i][fc] = __builtin_amdgcn_mfma_f32_16x16x32_bf16(
                af[i][kh], bfr[fc][kh], acc[2 * r + i][fc], 0, 0, 0);
      __builtin_amdgcn_s_setprio(0);
      __builtin_amdgcn_sched_barrier(0);
      __builtin_amdgcn_s_barrier();
      __builtin_amdgcn_sched_barrier(0);
    }
  }

  // epilogue: fixed-shift partials, wn-merge in LDS
  __syncthreads();
  float* sb = (float*)KQ;  // [256 q_local][4 wn][2]
  #pragma unroll
  for (int fr = 0; fr < 8; ++fr) {
    #pragma unroll
    for (int j = 0; j < 4; ++j) {
      float s4[4];
      #pragma unroll
      for (int fc = 0; fc < 4; ++fc) s4[fc] = acc[fr][fc][j] * 0.03125f;
      if (kt == 0 && wn == 0 && l15 == 0) s4[0] = 0.0f;  // mask global col 0
      float ps = 0.f, pv = 0.f;
      #pragma unroll
      for (int fc = 0; fc < 4; ++fc) {
        const float e = __expf(s4[fc] - 8.0f);
        ps += e; pv += e * vv[fc];
      }
      ps += __shfl_xor(ps, 1); pv += __shfl_xor(pv, 1);
      ps += __shfl_xor(ps, 2); pv += __shfl_xor(pv, 2);
      ps += __shfl_xor(ps, 4); pv += __shfl_xor(pv, 4);
      ps += __shfl_xor(ps, 8); pv += __shfl_xor(pv, 8);
      if (l15 == 0) {
        const int q = wm * 128 + fr * 16 + lq * 4 + j;
        sb[(q * 4 + wn) * 2 + 0] = ps;
        sb[(q * 4 + wn) * 2 + 1] = pv;
      }
    }
  }
  __syncthreads();
  if (tid < 256) {
    const int q = tid;
    float L = 0.f, O = 0.f;
    #pragma unroll
    for (int n = 0; n < 4; ++n) { L += sb[(q * 4 + n) * 2]; O += sb[(q * 4 + n) * 2 + 1]; }
    float* p = Pp + (((size_t)h * 8 + kt) * N_ + qt * 256 + q) * 2;
    p[0] = L; p[1] = O;
  }
}

// ---------------- merge 8 kt partials -> ctx (plain sums) ----------------
__global__ __launch_bounds__(256) void merge8(const float* __restrict__ Pp,
                                              float* __restrict__ ctx) {
  const int idx = blockIdx.x * 256 + threadIdx.x;  // [0, 32768)
  const int h = idx >> 11, q = idx & (N_ - 1);
  float L = 0.f, O = 0.f;
  #pragma unroll
  for (int kt = 0; kt < 8; ++kt) {
    const float* p = Pp + (((size_t)h * 8 + kt) * N_ + q) * 2;
    L += p[0]; O += p[1];
  }
  ctx[(size_t)q * H_ + h] = O / L;
}

// ---------------- out = ctx @ M + dec_b ----------------
__global__ __launch_bounds__(256) void final_kernel(
    const float* __restrict__ ctx, const float* __restrict__ M,
    const float* __restrict__ dec_b, float* __restrict__ out) {
  const int idx = blockIdx.x * 256 + threadIdx.x;
  const int c = idx & 1023;
  const float* cr = ctx + (size_t)(idx >> 10) * H_;
  float s = dec_b[c];
  #pragma unroll
  for (int h = 0; h < H_; ++h) s += cr[h] * M[h * 1024 + c];
  out[idx] = s;
}

extern "C" void kernel_launch(void* const* d_in, const int* in_sizes, int n_in,
                              void* d_out, int out_size, void* d_ws, size_t ws_size,
                              hipStream_t stream) {
  const float* X     = (const float*)d_in[0];
  const float* emb_w = (const float*)d_in[1];
  const float* emb_b = (const float*)d_in[2];
  const float* Wq    = (const float*)d_in[3];
  const float* Wk    = (const float*)d_in[4];
  const float* Wv    = (const float*)d_in[5];
  const float* Wo    = (const float*)d_in[6];
  const float* dec_b = (const float*)d_in[8];
  const float* dec_w = (const float*)d_in[7];
  float* out = (float*)d_out;
  (void)in_sizes; (void)n_in; (void)out_size;

  char* ws = (char*)d_ws;
  // persistent region: 41 MB
  unsigned short* Hbf = (unsigned short*)(ws);                              // 8 MB  [4096][1024]
  unsigned short* Wkq = (unsigned short*)(ws + ((size_t)8 << 20));          // 32 MB [16][1024][1024]
  float* Vb  = (float*)(ws + ((size_t)40 << 20));                          // 256 KB [2][16][2048]
  float* ctx = (float*)(ws + ((size_t)40 << 20) + ((size_t)256 << 10));    // 256 KB [4096][16]
  float* Mw  = (float*)(ws + ((size_t)40 << 20) + ((size_t)512 << 10));    // 64 KB  [16][1024]
  // scratch region S (64 MB), phase-aliased
  char* S = ws + ((size_t)41 << 20);
  unsigned short* Xbf  = (unsigned short*)(S);                              // 4 MB
  unsigned short* EbT  = (unsigned short*)(S + ((size_t)4 << 20));          // 1 MB
  unsigned short* Wqbf = (unsigned short*)(S);                              // 32 MB
  unsigned short* Wkbf = (unsigned short*)(S + ((size_t)32 << 20));         // 32 MB
  unsigned short* G    = (unsigned short*)(S);                              // 64 MB [16][2048][1024]
  // score partials live in d_out (dead until final_kernel): 16*8*2048*2*4 = 2.1 MB
  float* Pp = (float*)d_out;

  const size_t need = ((size_t)41 << 20) + ((size_t)64 << 20);  // 105 MB
  if (ws_size < need) return;  // clean fail -> diagnostic (ws too small)

  prep_kernel<<<2560, 256, 0, stream>>>(X, Xbf, emb_w, EbT);
  gemm_embed<<<dim3(8, 32), 256, 0, stream>>>(Xbf, EbT, emb_b, Hbf);
  // Wkq[h] = Wk[h] @ Wq[h]^T  (so that G = h @ Wkq^T = h @ (Wq Wk^T))
  cast_bf16x2<<<32768, 256, 0, stream>>>(Wq, Wk, Wqbf, Wkbf, H_ * D_ * D_);
  gemm_nt256<<<256, 512, 131072, stream>>>(Wkbf, Wqbf, Wkq, D_,
                                           (long)D_ * D_, (long)D_ * D_, (long)D_ * D_,
                                           4, 4, 1024);
  v_wodec_kernel<<<1088, 256, 0, stream>>>(Hbf, Wv, Vb, Wo, dec_w, Mw);

  for (int b = 0; b < B_; ++b) {
    const unsigned short* Hb = Hbf + (size_t)b * N_ * D_;
    gemm_nt256<<<512, 512, 131072, stream>>>(Hb, Wkq, G, D_,
                                             0L, (long)D_ * D_, (long)N_ * D_,
                                             4, 8, 1024);
    score_flash<<<1024, 512, 131072, stream>>>(G, Hb, Vb + (size_t)b * H_ * N_, Pp);
    merge8<<<128, 256, 0, stream>>>(Pp, ctx + (size_t)b * N_ * H_);
  }
  final_kernel<<<16384, 256, 0, stream>>>(ctx, Mw, dec_b, out);
}